// Round 2
// baseline (506.174 us; speedup 1.0000x reference)
//
#include <hip/hip_runtime.h>
#include <stdint.h>

#define NODES 65536
#define INCH 512
#define OCH 512   // NUM_HEADS * OUT_CH
#define HEADS 8
#define HD 64

typedef __attribute__((ext_vector_type(8))) short short8;
typedef __attribute__((ext_vector_type(4))) float f32x4;

__device__ __forceinline__ uint32_t pk2bf(float a, float b) {
  uint32_t ua = __builtin_bit_cast(uint32_t, a);
  uint32_t ub = __builtin_bit_cast(uint32_t, b);
  ua = (ua + 0x7FFFu + ((ua >> 16) & 1u)) >> 16;
  ub = (ub + 0x7FFFu + ((ub >> 16) & 1u)) >> 16;
  return (ua & 0xFFFFu) | (ub << 16);
}
__device__ __forceinline__ uint16_t f2bf(float a) {
  uint32_t ua = __builtin_bit_cast(uint32_t, a);
  return (uint16_t)((ua + 0x7FFFu + ((ua >> 16) & 1u)) >> 16);
}
__device__ __forceinline__ float bflo(uint32_t w) { return __builtin_bit_cast(float, w << 16); }
__device__ __forceinline__ float bfhi(uint32_t w) { return __builtin_bit_cast(float, w & 0xFFFF0000u); }

// ---------------------------------------------------------------------------
// K1: fused QKV projection GEMM. C = A @ W^T + b, stored bf16.
// Tile 128x128, BK=64, 256 threads (4 waves, 2x2 of 64x64 per wave).
// Epilogue fuses: ||Q||^2, ||K||^2 (atomics), ks_sum[512] (LDS + atomics).
// ---------------------------------------------------------------------------
__global__ __launch_bounds__(256) void k_gemm_qkv(
    const float* __restrict__ qin, const float* __restrict__ sin_,
    const float* __restrict__ Wq, const float* __restrict__ bq,
    const float* __restrict__ Wk, const float* __restrict__ bk,
    const float* __restrict__ Wv, const float* __restrict__ bv,
    uint16_t* __restrict__ Qb, uint16_t* __restrict__ Kb, uint16_t* __restrict__ Vb,
    float* __restrict__ norms /*[2]: qnorm2, knorm2*/,
    float* __restrict__ ks_sum /*[512]*/) {
  __shared__ uint16_t As[128 * 72];  // pad 64->72: byte-row-stride 144 (16B-aligned)
  __shared__ uint16_t Bs[128 * 72];
  __shared__ float red4[4];
  __shared__ float ksp[128];

  const int tid = threadIdx.x;
  const int blk = blockIdx.x;
  const int ct = blk % 12;
  const int rt = blk / 12;
  const int proj = ct >> 2;            // 0=Q 1=K 2=V
  const int cb = (ct & 3) * 128;       // col base within the 512-wide projection
  const float* A = (proj == 0) ? qin : sin_;
  const float* W = (proj == 0) ? Wq : (proj == 1) ? Wk : Wv;
  const float* Bi = (proj == 0) ? bq : (proj == 1) ? bk : bv;
  uint16_t* O = (proj == 0) ? Qb : (proj == 1) ? Kb : Vb;
  const int row0 = rt * 128;

  const int lane = tid & 63;
  const int w = tid >> 6;
  const int wr = w >> 1, wc = w & 1;
  const int l15 = lane & 15, lhi = lane >> 4;

  f32x4 acc[4][4];
#pragma unroll
  for (int m = 0; m < 4; ++m)
#pragma unroll
    for (int n = 0; n < 4; ++n) acc[m][n] = (f32x4){0.f, 0.f, 0.f, 0.f};

  for (int kt = 0; kt < 8; ++kt) {
    const int k0 = kt * 64;
#pragma unroll
    for (int i = 0; i < 8; ++i) {
      const int idx = tid + i * 256;
      const int r = idx >> 4, c4 = idx & 15;
      float4 va = *(const float4*)(A + (size_t)(row0 + r) * INCH + k0 + c4 * 4);
      uint2 pa;
      pa.x = pk2bf(va.x, va.y);
      pa.y = pk2bf(va.z, va.w);
      *(uint2*)(&As[r * 72 + c4 * 4]) = pa;
      float4 vb = *(const float4*)(W + (size_t)(cb + r) * INCH + k0 + c4 * 4);
      uint2 pb;
      pb.x = pk2bf(vb.x, vb.y);
      pb.y = pk2bf(vb.z, vb.w);
      *(uint2*)(&Bs[r * 72 + c4 * 4]) = pb;
    }
    __syncthreads();
#pragma unroll
    for (int kk = 0; kk < 2; ++kk) {
      short8 a[4], b[4];
#pragma unroll
      for (int m = 0; m < 4; ++m)
        a[m] = *(const short8*)(&As[(wr * 64 + m * 16 + l15) * 72 + kk * 32 + lhi * 8]);
#pragma unroll
      for (int n = 0; n < 4; ++n)
        b[n] = *(const short8*)(&Bs[(wc * 64 + n * 16 + l15) * 72 + kk * 32 + lhi * 8]);
#pragma unroll
      for (int m = 0; m < 4; ++m)
#pragma unroll
        for (int n = 0; n < 4; ++n)
          acc[m][n] = __builtin_amdgcn_mfma_f32_16x16x32_bf16(a[m], b[n], acc[m][n], 0, 0, 0);
    }
    __syncthreads();
  }

  // Epilogue: bias, bf16 store, fused reductions.
  float nrm = 0.f;
  float cs[4] = {0.f, 0.f, 0.f, 0.f};
#pragma unroll
  for (int n = 0; n < 4; ++n) {
    const int colg = cb + wc * 64 + n * 16 + l15;  // 0..511 within projection
    const float bias = Bi[colg];
#pragma unroll
    for (int m = 0; m < 4; ++m) {
      const int rowb = row0 + wr * 64 + m * 16 + lhi * 4;
#pragma unroll
      for (int r = 0; r < 4; ++r) {
        const float v = acc[m][n][r] + bias;
        O[(size_t)(rowb + r) * OCH + colg] = f2bf(v);
        nrm += v * v;
        cs[n] += v;
      }
    }
  }
#pragma unroll
  for (int o = 32; o >= 1; o >>= 1) nrm += __shfl_xor(nrm, o, 64);
  if (lane == 0) red4[w] = nrm;
  if (tid < 128) ksp[tid] = 0.f;
  __syncthreads();
  if (proj == 1) {
#pragma unroll
    for (int n = 0; n < 4; ++n) {
      cs[n] += __shfl_xor(cs[n], 16, 64);
      cs[n] += __shfl_xor(cs[n], 32, 64);
    }
    if (lhi == 0) {
#pragma unroll
      for (int n = 0; n < 4; ++n) atomicAdd(&ksp[wc * 64 + n * 16 + l15], cs[n]);
    }
  }
  __syncthreads();
  if (tid == 0 && proj < 2)
    atomicAdd(&norms[proj], red4[0] + red4[1] + red4[2] + red4[3]);
  if (proj == 1 && tid < 128) atomicAdd(&ks_sum[cb + tid], ksp[tid]);
}

// ---------------------------------------------------------------------------
// K2: kvs[h][m][d] = sum_n K[n][h*64+m] * V[n][h*64+d]   (raw, unnormalized)
// grid = 8 heads * 64 chunks (1024 rows each); 256 thr as 16x16, 4x4/thread.
// ---------------------------------------------------------------------------
__global__ __launch_bounds__(256) void k_kvs(
    const uint16_t* __restrict__ Kb, const uint16_t* __restrict__ Vb,
    float* __restrict__ kvs) {
  __shared__ uint16_t Ks[64 * 64];
  __shared__ uint16_t Vs[64 * 64];
  const int tid = threadIdx.x;
  const int h = blockIdx.x & 7;
  const int chunk = blockIdx.x >> 3;
  const int tm = tid >> 4, td = tid & 15;
  float acc[4][4];
#pragma unroll
  for (int a2 = 0; a2 < 4; ++a2)
#pragma unroll
    for (int b2 = 0; b2 < 4; ++b2) acc[a2][b2] = 0.f;

  for (int nb = 0; nb < 16; ++nb) {
    const int n0 = chunk * 1024 + nb * 64;
#pragma unroll
    for (int i = 0; i < 2; ++i) {
      const int id = tid + i * 256;
      const int row = id >> 3, c8 = id & 7;
      *(uint4*)(&Ks[row * 64 + c8 * 8]) =
          *(const uint4*)(Kb + (size_t)(n0 + row) * OCH + h * 64 + c8 * 8);
      *(uint4*)(&Vs[row * 64 + c8 * 8]) =
          *(const uint4*)(Vb + (size_t)(n0 + row) * OCH + h * 64 + c8 * 8);
    }
    __syncthreads();
    for (int nn = 0; nn < 64; ++nn) {
      const uint2 kw = *(const uint2*)(&Ks[nn * 64 + tm * 4]);
      const uint2 vw = *(const uint2*)(&Vs[nn * 64 + td * 4]);
      const float km[4] = {bflo(kw.x), bfhi(kw.x), bflo(kw.y), bfhi(kw.y)};
      const float vd[4] = {bflo(vw.x), bfhi(vw.x), bflo(vw.y), bfhi(vw.y)};
#pragma unroll
      for (int a2 = 0; a2 < 4; ++a2)
#pragma unroll
        for (int b2 = 0; b2 < 4; ++b2) acc[a2][b2] = fmaf(km[a2], vd[b2], acc[a2][b2]);
    }
    __syncthreads();
  }
#pragma unroll
  for (int a2 = 0; a2 < 4; ++a2)
#pragma unroll
    for (int b2 = 0; b2 < 4; ++b2)
      atomicAdd(&kvs[(size_t)(h * 64 + tm * 4 + a2) * 64 + td * 4 + b2], acc[a2][b2]);
}

// ---------------------------------------------------------------------------
// K3: out[n][d] = (1/8) sum_h (scale*(q_n . kvs_h[:,d]) + N*v[d]) / den_h
//     den_h = scale*(q_n . ks_sum_h) + N;  scale = 1/(|Q| * |K|)
// 1 thread = 1 node, 256 thr/block, 256 blocks (all CUs).
// kvs (f32, 128KB) + ks_sum staged in dynamic LDS; reads are wave-uniform
// broadcasts (same address across lanes -> no bank conflicts).
// ---------------------------------------------------------------------------
__global__ __launch_bounds__(256) void k_final(
    const uint16_t* __restrict__ Qb, const uint16_t* __restrict__ Vb,
    const float* __restrict__ kvs, const float* __restrict__ ks_sum,
    const float* __restrict__ norms, float* __restrict__ out) {
  extern __shared__ char smem[];
  float* kv = (float*)smem;                  // 8*64*64 f32 = 128KB
  float* kss = (float*)(smem + 131072);      // 512 f32
  const int tid = threadIdx.x;
#pragma unroll
  for (int i = 0; i < 128; ++i) kv[tid + i * 256] = kvs[tid + i * 256];
  kss[tid] = ks_sum[tid];
  kss[tid + 256] = ks_sum[tid + 256];
  __syncthreads();

  const float scale = 1.0f / (sqrtf(norms[0]) * sqrtf(norms[1]));
  const float Nf = 65536.0f;
  const int node = blockIdx.x * 256 + tid;
  const uint4* Qp = (const uint4*)(Qb + (size_t)node * OCH);
  const uint4* Vp = (const uint4*)(Vb + (size_t)node * OCH);

  float o[64];
#pragma unroll
  for (int d = 0; d < 64; ++d) o[d] = 0.f;

  for (int h = 0; h < HEADS; ++h) {
    // Each head = 64 bf16 = 8 uint4.
    uint4 qa[8], va[8];
#pragma unroll
    for (int i = 0; i < 8; ++i) {
      qa[i] = Qp[h * 8 + i];
      va[i] = Vp[h * 8 + i];
    }
    const float* kb = &kv[h * 64 * 64];
    const float* ks = &kss[h * 64];
    float den = 0.f;
#pragma unroll
    for (int i = 0; i < 8; ++i) {
      const uint32_t dw[4] = {qa[i].x, qa[i].y, qa[i].z, qa[i].w};
#pragma unroll
      for (int c = 0; c < 4; ++c) {
        const int m = i * 8 + c * 2;
        den = fmaf(bflo(dw[c]), ks[m], den);
        den = fmaf(bfhi(dw[c]), ks[m + 1], den);
      }
    }
    const float rden = 1.0f / (den * scale + Nf);
    const float qsc = scale * rden;
    const float vsc = Nf * rden;
#pragma unroll
    for (int i = 0; i < 8; ++i) {
      const uint32_t dw[4] = {qa[i].x, qa[i].y, qa[i].z, qa[i].w};
#pragma unroll
      for (int c = 0; c < 4; ++c) {
#pragma unroll
        for (int b = 0; b < 2; ++b) {
          const int m = i * 8 + c * 2 + b;
          const float qf = (b ? bfhi(dw[c]) : bflo(dw[c])) * qsc;
          const float* kr = kb + m * 64;
#pragma unroll
          for (int d4 = 0; d4 < 16; ++d4) {
            const float4 kvv = *(const float4*)(kr + d4 * 4);
            o[d4 * 4 + 0] = fmaf(qf, kvv.x, o[d4 * 4 + 0]);
            o[d4 * 4 + 1] = fmaf(qf, kvv.y, o[d4 * 4 + 1]);
            o[d4 * 4 + 2] = fmaf(qf, kvv.z, o[d4 * 4 + 2]);
            o[d4 * 4 + 3] = fmaf(qf, kvv.w, o[d4 * 4 + 3]);
          }
        }
      }
    }
#pragma unroll
    for (int i = 0; i < 8; ++i) {
      const uint32_t dw[4] = {va[i].x, va[i].y, va[i].z, va[i].w};
#pragma unroll
      for (int c = 0; c < 4; ++c) {
        const int d = i * 8 + c * 2;
        o[d] = fmaf(vsc, bflo(dw[c]), o[d]);
        o[d + 1] = fmaf(vsc, bfhi(dw[c]), o[d + 1]);
      }
    }
  }

  float* op = out + (size_t)node * 64;
#pragma unroll
  for (int d4 = 0; d4 < 16; ++d4) {
    float4 r;
    r.x = o[d4 * 4 + 0] * 0.125f;
    r.y = o[d4 * 4 + 1] * 0.125f;
    r.z = o[d4 * 4 + 2] * 0.125f;
    r.w = o[d4 * 4 + 3] * 0.125f;
    *(float4*)(op + d4 * 4) = r;
  }
}

// ---------------------------------------------------------------------------
extern "C" void kernel_launch(void* const* d_in, const int* in_sizes, int n_in,
                              void* d_out, int out_size, void* d_ws, size_t ws_size,
                              hipStream_t stream) {
  const float* qin = (const float*)d_in[0];
  const float* sin_ = (const float*)d_in[1];
  const float* Wq = (const float*)d_in[2];
  const float* bq = (const float*)d_in[3];
  const float* Wk = (const float*)d_in[4];
  const float* bk = (const float*)d_in[5];
  const float* Wv = (const float*)d_in[6];
  const float* bv = (const float*)d_in[7];
  float* out = (float*)d_out;

  char* ws = (char*)d_ws;
  float* kvs = (float*)ws;                        // 131072 B
  float* ks_sum = (float*)(ws + 131072);          // 2048 B
  float* norms = (float*)(ws + 133120);           // 8 B
  uint16_t* Qb = (uint16_t*)(ws + (1 << 20));                    // 64 MB
  uint16_t* Kb = (uint16_t*)(ws + (1 << 20) + (size_t)67108864); // 64 MB
  uint16_t* Vb = (uint16_t*)(ws + (1 << 20) + (size_t)134217728);// 64 MB

  // Accumulators must be zeroed every call (graph replays reuse ws).
  hipMemsetAsync(d_ws, 0, 133128, stream);

  k_gemm_qkv<<<dim3(512 * 12), dim3(256), 0, stream>>>(
      qin, sin_, Wq, bq, Wk, bk, Wv, bv, Qb, Kb, Vb, norms, ks_sum);

  k_kvs<<<dim3(512), dim3(256), 0, stream>>>(Kb, Vb, kvs);

  k_final<<<dim3(256), dim3(256), 133120, stream>>>(Qb, Vb, kvs, ks_sum, norms, out);
}